// Round 2
// baseline (1135.769 us; speedup 1.0000x reference)
//
#include <hip/hip_runtime.h>
#include <math.h>

#define TPB 256
constexpr int Bb = 8, Mm = 2048, Nn = 8192, HID = 128;

// Opaque VGPR zero: forces weight loads onto the vector-memory path
// (uniform-address global_load_dwordx4 -> single L1 transaction + broadcast,
// deep vmcnt pipelining) instead of the scalar pipe.
__device__ __forceinline__ int vzero() { int v; asm("v_mov_b32 %0, 0" : "=v"(v)); return v; }
__device__ __forceinline__ float4 ldg4(const float* __restrict__ p, int idx4, int vz) {
  return ((const float4*)p)[idx4 + vz];
}

// --- K0: fused weights. fc2 and deconv are consecutive LINEAR layers:
//   ht[ot] = relu( sum_j h[j]*Wf[ot][j] + Cf[ot] )
//   Wf[ot][j] = sum_i W2[i][j]*Wd[i][ot];  Cf[ot] = sum_i b2[i]*Wd[i][ot] + bd[ot>>1]
__global__ __launch_bounds__(TPB) void prep_kernel(const float* __restrict__ W2,
    const float* __restrict__ b2, const float* __restrict__ Wd,
    const float* __restrict__ bd, float* __restrict__ Wf, float* __restrict__ Cf) {
  int idx = blockIdx.x * TPB + threadIdx.x;   // 0..32767
  int ot = idx >> 7, j = idx & 127;
  float acc = 0.f;
  for (int i = 0; i < HID; ++i)
    acc = fmaf(W2[i * HID + j], Wd[i * 256 + ot], acc);
  Wf[idx] = acc;
  if (j == 0) {
    float c = bd[ot >> 1];
    for (int i = 0; i < HID; ++i) c = fmaf(b2[i], Wd[i * 256 + ot], c);
    Cf[ot] = c;
  }
}

// --- K1: exact 8-NN + neighbor mean -> {pred, nmean} (6 floats) IN d_out ----
__global__ __launch_bounds__(TPB) void knn_kernel(const float* __restrict__ partial,
                                                  const float* __restrict__ predicted,
                                                  float* __restrict__ outp) {
  __shared__ float4 pts[Mm];                  // 32 KiB {x,y,z,|p|^2}
  const int b  = blockIdx.x >> 5;
  const int qt = blockIdx.x & 31;
  const float* pb = partial + (size_t)b * Mm * 3;
  for (int i = threadIdx.x; i < Mm; i += TPB) {
    float x = pb[3 * i], y = pb[3 * i + 1], z = pb[3 * i + 2];
    pts[i] = make_float4(x, y, z, fmaf(x, x, fmaf(y, y, z * z)));
  }
  __syncthreads();

  const int q = qt * TPB + threadIdx.x;
  const float* pq = predicted + ((size_t)b * Nn + q) * 3;
  const float qx = pq[0], qy = pq[1], qz = pq[2];
  const float pn2 = fmaf(qx, qx, fmaf(qy, qy, qz * qz));

  float v0 = INFINITY, v1 = INFINITY, v2 = INFINITY, v3 = INFINITY,
        v4 = INFINITY, v5 = INFINITY, v6 = INFINITY, v7 = INFINITY;
  #pragma unroll 4
  for (int m = 0; m < Mm; ++m) {
    float4 p = pts[m];                        // wave-uniform -> LDS broadcast
    float dot = fmaf(qx, p.x, fmaf(qy, p.y, qz * p.z));
    float d2 = fmaf(-2.f, dot, pn2) + p.w;
    if (d2 < v0) {
      v0 = fmaxf(v1, fminf(v0, d2));
      v1 = fmaxf(v2, fminf(v1, d2));
      v2 = fmaxf(v3, fminf(v2, d2));
      v3 = fmaxf(v4, fminf(v3, d2));
      v4 = fmaxf(v5, fminf(v4, d2));
      v5 = fmaxf(v6, fminf(v5, d2));
      v6 = fmaxf(v7, fminf(v6, d2));
      v7 = fminf(v7, d2);
    }
  }
  const float t8 = v0;

  float sx = 0.f, sy = 0.f, sz = 0.f, ex = 0.f, ey = 0.f, ez = 0.f;
  int cl = 0, ce = 0;
  #pragma unroll 4
  for (int m = 0; m < Mm; ++m) {
    float4 p = pts[m];
    float dot = fmaf(qx, p.x, fmaf(qy, p.y, qz * p.z));
    float d2 = fmaf(-2.f, dot, pn2) + p.w;    // identical op sequence -> bitwise equal
    if (d2 < t8)        { sx += p.x; sy += p.y; sz += p.z; ++cl; }
    else if (d2 == t8)  { ex += p.x; ey += p.y; ez += p.z; ++ce; }
  }
  if (cl + ce != 8) {                         // tie overflow: keep earliest indices
    ex = ey = ez = 0.f; int need = 8 - cl, got = 0;
    for (int m = 0; m < Mm && got < need; ++m) {
      float4 p = pts[m];
      float dot = fmaf(qx, p.x, fmaf(qy, p.y, qz * p.z));
      float d2 = fmaf(-2.f, dot, pn2) + p.w;
      if (d2 == t8) { ex += p.x; ey += p.y; ez += p.z; ++got; }
    }
  }
  float2* co = (float2*)(outp + (size_t)(b * Nn + q) * 6);
  co[0] = make_float2(qx, qy);
  co[1] = make_float2(qz, (sx + ex) * 0.125f);
  co[2] = make_float2((sy + ey) * 0.125f, (sz + ez) * 0.125f);
}

// --- K2: fc1+relu -> fused(fc2·deconv)+relu -> 1x1 conv -> +pred, in-place in d_out
__global__ __launch_bounds__(TPB) void mlp_kernel(const float* __restrict__ W1,
    const float* __restrict__ b1, const float* __restrict__ Wf,
    const float* __restrict__ Cf, const float* __restrict__ Wc,
    const float* __restrict__ bc, float* __restrict__ outp) {
  const int row = blockIdx.x * TPB + threadIdx.x;
  const int vz = vzero();
  float2* rp = (float2*)(outp + (size_t)row * 6);
  float2 r0 = rp[0], r1 = rp[1], r2 = rp[2];   // own 6 floats only -> RMW safe
  const float c0 = r0.x, c1 = r0.y, c2 = r1.x, c3 = r1.y, c4 = r2.x, c5 = r2.y;

  // fc1 + relu: h[128] as 32 static float4 registers
  float4 h4[32];
  #pragma unroll
  for (int j4 = 0; j4 < 32; ++j4) {
    float4 bb = ((const float4*)b1)[j4];
    float4 w0 = ldg4(W1, j4 * 6 + 0, vz), w1 = ldg4(W1, j4 * 6 + 1, vz),
           w2 = ldg4(W1, j4 * 6 + 2, vz), w3 = ldg4(W1, j4 * 6 + 3, vz),
           w4 = ldg4(W1, j4 * 6 + 4, vz), w5 = ldg4(W1, j4 * 6 + 5, vz);
    float a0 = bb.x, a1 = bb.y, a2 = bb.z, a3 = bb.w;
    a0 = fmaf(c0, w0.x, a0); a0 = fmaf(c1, w0.y, a0); a0 = fmaf(c2, w0.z, a0);
    a0 = fmaf(c3, w0.w, a0); a0 = fmaf(c4, w1.x, a0); a0 = fmaf(c5, w1.y, a0);
    a1 = fmaf(c0, w1.z, a1); a1 = fmaf(c1, w1.w, a1); a1 = fmaf(c2, w2.x, a1);
    a1 = fmaf(c3, w2.y, a1); a1 = fmaf(c4, w2.z, a1); a1 = fmaf(c5, w2.w, a1);
    a2 = fmaf(c0, w3.x, a2); a2 = fmaf(c1, w3.y, a2); a2 = fmaf(c2, w3.z, a2);
    a2 = fmaf(c3, w3.w, a2); a2 = fmaf(c4, w4.x, a2); a2 = fmaf(c5, w4.y, a2);
    a3 = fmaf(c0, w4.z, a3); a3 = fmaf(c1, w4.w, a3); a3 = fmaf(c2, w5.x, a3);
    a3 = fmaf(c3, w5.y, a3); a3 = fmaf(c4, w5.z, a3); a3 = fmaf(c5, w5.w, a3);
    h4[j4] = make_float4(fmaxf(a0, 0.f), fmaxf(a1, 0.f), fmaxf(a2, 0.f), fmaxf(a3, 0.f));
  }

  // fused layer (dot-128 per (o,t)) + relu + 1x1 conv accumulation
  float o00 = 0.f, o10 = 0.f, o20 = 0.f, o01 = 0.f, o11 = 0.f, o21 = 0.f;
  for (int oo = 0; oo < 32; ++oo) {
    #pragma unroll
    for (int kk = 0; kk < 4; ++kk) {
      const int o = oo * 4 + kk;
      float a0 = Cf[2 * o], a1 = Cf[2 * o + 1];
      #pragma unroll
      for (int c = 0; c < 32; ++c) {
        float4 w0 = ldg4(Wf, (2 * o) * 32 + c, vz);
        float4 w1 = ldg4(Wf, (2 * o + 1) * 32 + c, vz);
        float4 hh = h4[c];                     // static index
        a0 = fmaf(hh.x, w0.x, a0); a1 = fmaf(hh.x, w1.x, a1);
        a0 = fmaf(hh.y, w0.y, a0); a1 = fmaf(hh.y, w1.y, a1);
        a0 = fmaf(hh.z, w0.z, a0); a1 = fmaf(hh.z, w1.z, a1);
        a0 = fmaf(hh.w, w0.w, a0); a1 = fmaf(hh.w, w1.w, a1);
      }
      a0 = fmaxf(a0, 0.f); a1 = fmaxf(a1, 0.f);
      const float wc0 = Wc[o], wc1 = Wc[HID + o], wc2 = Wc[2 * HID + o];
      o00 = fmaf(a0, wc0, o00); o10 = fmaf(a0, wc1, o10); o20 = fmaf(a0, wc2, o20);
      o01 = fmaf(a1, wc0, o01); o11 = fmaf(a1, wc1, o11); o21 = fmaf(a1, wc2, o21);
    }
  }
  rp[0] = make_float2(c0 + o00 + bc[0], c1 + o10 + bc[1]);
  rp[1] = make_float2(c2 + o20 + bc[2], c0 + o01 + bc[0]);
  rp[2] = make_float2(c1 + o11 + bc[1], c2 + o21 + bc[2]);
}

// --- correctness-only fallback if ws is too small for Wf/Cf (no ws use) -----
__global__ __launch_bounds__(TPB) void mlp_fallback(
    const float* __restrict__ W1, const float* __restrict__ b1,
    const float* __restrict__ W2, const float* __restrict__ b2,
    const float* __restrict__ Wd, const float* __restrict__ bd,
    const float* __restrict__ Wc, const float* __restrict__ bc,
    float* __restrict__ outp) {
  const int row = blockIdx.x * TPB + threadIdx.x;
  float2* rp = (float2*)(outp + (size_t)row * 6);
  float2 r0 = rp[0], r1 = rp[1], r2 = rp[2];
  float cc[6] = {r0.x, r0.y, r1.x, r1.y, r2.x, r2.y};
  float h[HID];
  for (int j = 0; j < HID; ++j) {
    float a = b1[j];
    for (int c = 0; c < 6; ++c) a = fmaf(cc[c], W1[j * 6 + c], a);
    h[j] = fmaxf(a, 0.f);
  }
  float sd[HID];
  for (int i = 0; i < HID; ++i) {
    float a = b2[i];
    for (int j = 0; j < HID; ++j) a = fmaf(h[j], W2[i * HID + j], a);
    sd[i] = a;
  }
  float ov[3][2] = {};
  for (int oc = 0; oc < HID; ++oc)
    for (int t = 0; t < 2; ++t) {
      float a = bd[oc];
      for (int i = 0; i < HID; ++i) a = fmaf(sd[i], Wd[i * 256 + oc * 2 + t], a);
      a = fmaxf(a, 0.f);
      for (int c = 0; c < 3; ++c) ov[c][t] = fmaf(a, Wc[c * HID + oc], ov[c][t]);
    }
  rp[0] = make_float2(cc[0] + ov[0][0] + bc[0], cc[1] + ov[1][0] + bc[1]);
  rp[1] = make_float2(cc[2] + ov[2][0] + bc[2], cc[0] + ov[0][1] + bc[0]);
  rp[2] = make_float2(cc[1] + ov[1][1] + bc[1], cc[2] + ov[2][1] + bc[2]);
}

extern "C" void kernel_launch(void* const* d_in, const int* in_sizes, int n_in,
                              void* d_out, int out_size, void* d_ws, size_t ws_size,
                              hipStream_t stream) {
  const float* partial   = (const float*)d_in[0];
  const float* predicted = (const float*)d_in[1];
  const float* W1 = (const float*)d_in[2];
  const float* b1 = (const float*)d_in[3];
  const float* W2 = (const float*)d_in[4];
  const float* b2 = (const float*)d_in[5];
  const float* Wd = (const float*)d_in[6];
  const float* bd = (const float*)d_in[7];
  const float* Wc = (const float*)d_in[8];
  const float* bc = (const float*)d_in[9];
  float* outp = (float*)d_out;

  float* Wf = (float*)d_ws;                   // 32768 f32 = 128 KiB
  float* Cf = Wf + 32768;                     // 256 f32 = 1 KiB
  const bool fits = ws_size >= (size_t)(33024 * sizeof(float));  // constant per run

  if (fits)
    hipLaunchKernelGGL(prep_kernel, dim3(128), dim3(TPB), 0, stream,
                       W2, b2, Wd, bd, Wf, Cf);
  hipLaunchKernelGGL(knn_kernel, dim3(Bb * (Nn / TPB)), dim3(TPB), 0, stream,
                     partial, predicted, outp);
  if (fits)
    hipLaunchKernelGGL(mlp_kernel, dim3((Bb * Nn) / TPB), dim3(TPB), 0, stream,
                       W1, b1, Wf, Cf, Wc, bc, outp);
  else
    hipLaunchKernelGGL(mlp_fallback, dim3((Bb * Nn) / TPB), dim3(TPB), 0, stream,
                       W1, b1, W2, b2, Wd, bd, Wc, bc, outp);
}

// Round 3
// 334.591 us; speedup vs baseline: 3.3945x; 3.3945x over previous
//
#include <hip/hip_runtime.h>
#include <hip/hip_bf16.h>
#include <math.h>

#define TPB 256
constexpr int Bb = 8, Mm = 2048, Nn = 8192, HID = 128;

typedef __attribute__((ext_vector_type(8))) short short8;
typedef __attribute__((ext_vector_type(4))) float f32x4;

__device__ __forceinline__ int vzero() { int v; asm("v_mov_b32 %0, 0" : "=v"(v)); return v; }
__device__ __forceinline__ float4 ldg4(const float* __restrict__ p, int idx4, int vz) {
  return ((const float4*)p)[idx4 + vz];
}
__device__ __forceinline__ unsigned short f2b(float x) {
  __hip_bfloat16 h = __float2bfloat16(x);
  return *reinterpret_cast<unsigned short*>(&h);
}

// --- K0: pack fused weights Wf = W2^T·Wd into MFMA-B fragment order (bf16) ---
// Bpack[f][lane][j]: f = (chunk*4+ks)*4+n ; element = Wf[col][k],
//   k = ks*32 + (lane>>4)*8 + j ; col = chunk*64 + n*16 + (lane&15)
__global__ __launch_bounds__(TPB) void prep2_kernel(const float* __restrict__ W2,
    const float* __restrict__ b2, const float* __restrict__ Wd,
    const float* __restrict__ bd, unsigned short* __restrict__ Bpack,
    float* __restrict__ Cf) {
  int idx = blockIdx.x * TPB + threadIdx.x;   // 0..32767
  int f = idx >> 9, r = idx & 511, lane = r >> 3, j = r & 7;
  int chunk = f >> 4, ks = (f >> 2) & 3, n = f & 3;
  int k   = ks * 32 + (lane >> 4) * 8 + j;
  int col = chunk * 64 + n * 16 + (lane & 15);
  float acc = 0.f;
  for (int i = 0; i < HID; ++i)
    acc = fmaf(W2[i * HID + k], Wd[i * 256 + col], acc);
  Bpack[idx] = f2b(acc);
  if (idx < 256) {                            // fused bias Cf[ot] (f32)
    float c = bd[idx >> 1];
    for (int i = 0; i < HID; ++i) c = fmaf(b2[i], Wd[i * 256 + idx], c);
    Cf[idx] = c;
  }
}

// --- K1: exact 8-NN, split-M (2 threads/query), -> 6 floats per row in d_out
__global__ __launch_bounds__(TPB) void knn2_kernel(const float* __restrict__ partial,
                                                   const float* __restrict__ predicted,
                                                   float* __restrict__ outp) {
  __shared__ float4 pts[Mm];                  // 32 KiB {x,y,z,|p|^2}
  __shared__ float4 lists[TPB][2];            // 8 KiB sorted-8 per thread
  __shared__ float4 parts[128][2];            // 4 KiB partial sums
  const int b  = blockIdx.x >> 6;             // 512 blocks: 8 b x 64 qt
  const int qt = blockIdx.x & 63;
  const float* pb = partial + (size_t)b * Mm * 3;
  for (int i = threadIdx.x; i < Mm; i += TPB) {
    float x = pb[3 * i], y = pb[3 * i + 1], z = pb[3 * i + 2];
    pts[i] = make_float4(x, y, z, fmaf(x, x, fmaf(y, y, z * z)));
  }
  __syncthreads();

  const int half = threadIdx.x >> 7, qi = threadIdx.x & 127;
  const int q = qt * 128 + qi;
  const float* pq = predicted + ((size_t)b * Nn + q) * 3;
  const float qx = pq[0], qy = pq[1], qz = pq[2];
  const float pn2 = fmaf(qx, qx, fmaf(qy, qy, qz * qz));
  const int m0 = half * 1024;

  float v0 = INFINITY, v1 = INFINITY, v2 = INFINITY, v3 = INFINITY,
        v4 = INFINITY, v5 = INFINITY, v6 = INFINITY, v7 = INFINITY;
  #pragma unroll 4
  for (int mm = 0; mm < 1024; ++mm) {
    float4 p = pts[m0 + mm];                  // wave-uniform -> broadcast
    float dot = fmaf(qx, p.x, fmaf(qy, p.y, qz * p.z));
    float d2 = fmaf(-2.f, dot, pn2) + p.w;
    if (d2 < v0) {                            // sorted-desc insert network
      v0 = fmaxf(v1, fminf(v0, d2));
      v1 = fmaxf(v2, fminf(v1, d2));
      v2 = fmaxf(v3, fminf(v2, d2));
      v3 = fmaxf(v4, fminf(v3, d2));
      v4 = fmaxf(v5, fminf(v4, d2));
      v5 = fmaxf(v6, fminf(v5, d2));
      v6 = fmaxf(v7, fminf(v6, d2));
      v7 = fminf(v7, d2);
    }
  }
  lists[threadIdx.x][0] = make_float4(v0, v1, v2, v3);
  lists[threadIdx.x][1] = make_float4(v4, v5, v6, v7);
  __syncthreads();
  const float4 pa = lists[threadIdx.x ^ 128][0];
  const float4 pb4 = lists[threadIdx.x ^ 128][1];
  // merged 8th-smallest of two sorted-desc lists: max_j min(v_j, p_{7-j})
  const float t8 = fmaxf(
      fmaxf(fmaxf(fminf(v0, pb4.w), fminf(v1, pb4.z)),
            fmaxf(fminf(v2, pb4.y), fminf(v3, pb4.x))),
      fmaxf(fmaxf(fminf(v4, pa.w), fminf(v5, pa.z)),
            fmaxf(fminf(v6, pa.y), fminf(v7, pa.x))));

  float sx = 0.f, sy = 0.f, sz = 0.f, ex = 0.f, ey = 0.f, ez = 0.f;
  int cl = 0, ce = 0;
  #pragma unroll 4
  for (int mm = 0; mm < 1024; ++mm) {
    float4 p = pts[m0 + mm];
    float dot = fmaf(qx, p.x, fmaf(qy, p.y, qz * p.z));
    float d2 = fmaf(-2.f, dot, pn2) + p.w;    // bitwise-identical sequence
    if (d2 < t8)        { sx += p.x; sy += p.y; sz += p.z; ++cl; }
    else if (d2 == t8)  { ex += p.x; ey += p.y; ez += p.z; ++ce; }
  }
  if (half) {
    parts[qi][0] = make_float4(sx, sy, sz, (float)cl);
    parts[qi][1] = make_float4(ex, ey, ez, (float)ce);
  }
  __syncthreads();
  if (!half) {
    float4 u0 = parts[qi][0], u1 = parts[qi][1];
    sx += u0.x; sy += u0.y; sz += u0.z; cl += (int)u0.w;
    ex += u1.x; ey += u1.y; ez += u1.z; ce += (int)u1.w;
    if (cl + ce != 8) {                       // rare tie overflow: earliest wins
      ex = ey = ez = 0.f; int need = 8 - cl, got = 0;
      for (int m = 0; m < Mm && got < need; ++m) {
        float4 p = pts[m];
        float dot = fmaf(qx, p.x, fmaf(qy, p.y, qz * p.z));
        float d2 = fmaf(-2.f, dot, pn2) + p.w;
        if (d2 == t8) { ex += p.x; ey += p.y; ez += p.z; ++got; }
      }
    }
    float2* co = (float2*)(outp + ((size_t)b * Nn + q) * 6);
    co[0] = make_float2(qx, qy);
    co[1] = make_float2(qz, (sx + ex) * 0.125f);
    co[2] = make_float2((sy + ey) * 0.125f, (sz + ez) * 0.125f);
  }
}

// --- K2: fc1(regs) -> A to LDS(bf16,swizzled) -> MFMA GEMM vs Bpack -> epilogue
__global__ __launch_bounds__(TPB) void mlp_mfma(const float* __restrict__ W1,
    const float* __restrict__ b1, const unsigned short* __restrict__ Bpack,
    const float* __restrict__ Cf, const float* __restrict__ Wc,
    const float* __restrict__ bc, float* __restrict__ outp) {
  extern __shared__ char Alds[];              // 65536 B: A[256 rows][128 k] bf16
  const int tid = threadIdx.x;
  const int row0 = blockIdx.x * TPB;
  const int vz = vzero();

  { // phase 1: fc1 + relu for row = row0 + tid; stage bf16 row to LDS
    const float* rp = outp + (size_t)(row0 + tid) * 6;
    float2 r0 = *(const float2*)rp, r1 = *(const float2*)(rp + 2),
           r2 = *(const float2*)(rp + 4);
    const float c0 = r0.x, c1 = r0.y, c2 = r1.x, c3 = r1.y, c4 = r2.x, c5 = r2.y;
    float4 h4[32];
    #pragma unroll
    for (int j4 = 0; j4 < 32; ++j4) {
      float4 bb = ((const float4*)b1)[j4];
      float4 w0 = ldg4(W1, j4 * 6 + 0, vz), w1 = ldg4(W1, j4 * 6 + 1, vz),
             w2 = ldg4(W1, j4 * 6 + 2, vz), w3 = ldg4(W1, j4 * 6 + 3, vz),
             w4 = ldg4(W1, j4 * 6 + 4, vz), w5 = ldg4(W1, j4 * 6 + 5, vz);
      float a0 = bb.x, a1 = bb.y, a2 = bb.z, a3 = bb.w;
      a0 = fmaf(c0, w0.x, a0); a0 = fmaf(c1, w0.y, a0); a0 = fmaf(c2, w0.z, a0);
      a0 = fmaf(c3, w0.w, a0); a0 = fmaf(c4, w1.x, a0); a0 = fmaf(c5, w1.y, a0);
      a1 = fmaf(c0, w1.z, a1); a1 = fmaf(c1, w1.w, a1); a1 = fmaf(c2, w2.x, a1);
      a1 = fmaf(c3, w2.y, a1); a1 = fmaf(c4, w2.z, a1); a1 = fmaf(c5, w2.w, a1);
      a2 = fmaf(c0, w3.x, a2); a2 = fmaf(c1, w3.y, a2); a2 = fmaf(c2, w3.z, a2);
      a2 = fmaf(c3, w3.w, a2); a2 = fmaf(c4, w4.x, a2); a2 = fmaf(c5, w4.y, a2);
      a3 = fmaf(c0, w4.z, a3); a3 = fmaf(c1, w4.w, a3); a3 = fmaf(c2, w5.x, a3);
      a3 = fmaf(c3, w5.y, a3); a3 = fmaf(c4, w5.z, a3); a3 = fmaf(c5, w5.w, a3);
      h4[j4] = make_float4(fmaxf(a0, 0.f), fmaxf(a1, 0.f), fmaxf(a2, 0.f), fmaxf(a3, 0.f));
    }
    #pragma unroll
    for (int c = 0; c < 16; ++c) {            // 16 B chunks, XOR-swizzled
      float4 lo = h4[c * 2], hi = h4[c * 2 + 1];
      union { unsigned short us[8]; uint4 v; } pk;
      pk.us[0] = f2b(lo.x); pk.us[1] = f2b(lo.y); pk.us[2] = f2b(lo.z); pk.us[3] = f2b(lo.w);
      pk.us[4] = f2b(hi.x); pk.us[5] = f2b(hi.y); pk.us[6] = f2b(hi.z); pk.us[7] = f2b(hi.w);
      int byte = tid * 256 + ((c * 16) ^ ((tid & 7) << 4));
      *(uint4*)(Alds + byte) = pk.v;
    }
  }
  __syncthreads();

  // phase 2: wave computes rows [row0+wid*64, +64) x 256 cols via MFMA
  const int lane = tid & 63, wid = tid >> 6;
  const int g = lane >> 4, cidx = lane & 15;
  float ac[4][4][3] = {};                     // [m][i][c], static-indexed

  for (int chunk = 0; chunk < 4; ++chunk) {
    f32x4 acc[4][4];
    #pragma unroll
    for (int n = 0; n < 4; ++n) {
      float cfv = Cf[chunk * 64 + n * 16 + cidx];
      #pragma unroll
      for (int m = 0; m < 4; ++m) acc[m][n] = (f32x4){cfv, cfv, cfv, cfv};
    }
    #pragma unroll
    for (int ks = 0; ks < 4; ++ks) {
      short8 af[4];
      #pragma unroll
      for (int m = 0; m < 4; ++m) {           // A: row=cidx+16m, k=g*8+j
        int r = wid * 64 + m * 16 + cidx;
        int byte = r * 256 + ((ks * 64 + g * 16) ^ ((r & 7) << 4));
        af[m] = *(const short8*)(Alds + byte);
      }
      short8 bf[4];
      #pragma unroll
      for (int n = 0; n < 4; ++n)             // B: fragment-order, coalesced
        bf[n] = *(const short8*)((const char*)Bpack +
                 (((chunk * 4 + ks) * 4 + n) * 1024) + lane * 16);
      #pragma unroll
      for (int m = 0; m < 4; ++m)
        #pragma unroll
        for (int n = 0; n < 4; ++n)
          acc[m][n] = __builtin_amdgcn_mfma_f32_16x16x32_bf16(af[m], bf[n], acc[m][n], 0, 0, 0);
    }
    #pragma unroll
    for (int n = 0; n < 4; ++n) {             // relu + 1x1-conv fold
      int ot = chunk * 64 + n * 16 + cidx;
      int o = ot >> 1;
      float wc0 = Wc[o], wc1 = Wc[HID + o], wc2 = Wc[2 * HID + o];
      #pragma unroll
      for (int m = 0; m < 4; ++m) {
        #pragma unroll
        for (int i = 0; i < 4; ++i) {
          float v = fmaxf(acc[m][n][i], 0.f);
          ac[m][i][0] = fmaf(v, wc0, ac[m][i][0]);
          ac[m][i][1] = fmaf(v, wc1, ac[m][i][1]);
          ac[m][i][2] = fmaf(v, wc2, ac[m][i][2]);
        }
      }
    }
  }

  const float bc0 = bc[0], bc1 = bc[1], bc2 = bc[2];
  #pragma unroll
  for (int m = 0; m < 4; ++m) {
    #pragma unroll
    for (int i = 0; i < 4; ++i) {
      float s0 = ac[m][i][0], s1 = ac[m][i][1], s2 = ac[m][i][2];
      s0 += __shfl_xor(s0, 2); s0 += __shfl_xor(s0, 4); s0 += __shfl_xor(s0, 8);
      s1 += __shfl_xor(s1, 2); s1 += __shfl_xor(s1, 4); s1 += __shfl_xor(s1, 8);
      s2 += __shfl_xor(s2, 2); s2 += __shfl_xor(s2, 4); s2 += __shfl_xor(s2, 8);
      float o0 = __shfl_xor(s0, 1), o1 = __shfl_xor(s1, 1), o2 = __shfl_xor(s2, 1);
      const bool odd = lane & 1;               // col parity == t
      float t00 = odd ? o0 : s0, t01 = odd ? o1 : s1, t02 = odd ? o2 : s2;
      float t10 = odd ? s0 : o0, t11 = odd ? s1 : o1, t12 = odd ? s2 : o2;
      if (cidx == m * 4 + i) {                 // one lane per g writes its row
        int row = row0 + wid * 64 + m * 16 + g * 4 + i;
        float* rp = outp + (size_t)row * 6;
        float px = rp[0], py = rp[1], pz = rp[2];
        rp[0] = px + t00 + bc0; rp[1] = py + t01 + bc1; rp[2] = pz + t02 + bc2;
        rp[3] = px + t10 + bc0; rp[4] = py + t11 + bc1; rp[5] = pz + t12 + bc2;
      }
    }
  }
}

// --- correctness-only fallback if ws too small (no ws use) ------------------
__global__ __launch_bounds__(TPB) void mlp_fallback(
    const float* __restrict__ W1, const float* __restrict__ b1,
    const float* __restrict__ W2, const float* __restrict__ b2,
    const float* __restrict__ Wd, const float* __restrict__ bd,
    const float* __restrict__ Wc, const float* __restrict__ bc,
    float* __restrict__ outp) {
  const int row = blockIdx.x * TPB + threadIdx.x;
  float2* rp = (float2*)(outp + (size_t)row * 6);
  float2 r0 = rp[0], r1 = rp[1], r2 = rp[2];
  float cc[6] = {r0.x, r0.y, r1.x, r1.y, r2.x, r2.y};
  float h[HID];
  for (int j = 0; j < HID; ++j) {
    float a = b1[j];
    for (int c = 0; c < 6; ++c) a = fmaf(cc[c], W1[j * 6 + c], a);
    h[j] = fmaxf(a, 0.f);
  }
  float sd[HID];
  for (int i = 0; i < HID; ++i) {
    float a = b2[i];
    for (int j = 0; j < HID; ++j) a = fmaf(h[j], W2[i * HID + j], a);
    sd[i] = a;
  }
  float ov[3][2] = {};
  for (int oc = 0; oc < HID; ++oc)
    for (int t = 0; t < 2; ++t) {
      float a = bd[oc];
      for (int i = 0; i < HID; ++i) a = fmaf(sd[i], Wd[i * 256 + oc * 2 + t], a);
      a = fmaxf(a, 0.f);
      for (int c = 0; c < 3; ++c) ov[c][t] = fmaf(a, Wc[c * HID + oc], ov[c][t]);
    }
  rp[0] = make_float2(cc[0] + ov[0][0] + bc[0], cc[1] + ov[1][0] + bc[1]);
  rp[1] = make_float2(cc[2] + ov[2][0] + bc[2], cc[0] + ov[0][1] + bc[0]);
  rp[2] = make_float2(cc[1] + ov[1][1] + bc[1], cc[2] + ov[2][1] + bc[2]);
}

extern "C" void kernel_launch(void* const* d_in, const int* in_sizes, int n_in,
                              void* d_out, int out_size, void* d_ws, size_t ws_size,
                              hipStream_t stream) {
  const float* partial   = (const float*)d_in[0];
  const float* predicted = (const float*)d_in[1];
  const float* W1 = (const float*)d_in[2];
  const float* b1 = (const float*)d_in[3];
  const float* W2 = (const float*)d_in[4];
  const float* b2 = (const float*)d_in[5];
  const float* Wd = (const float*)d_in[6];
  const float* bd = (const float*)d_in[7];
  const float* Wc = (const float*)d_in[8];
  const float* bc = (const float*)d_in[9];
  float* outp = (float*)d_out;

  unsigned short* Bpack = (unsigned short*)d_ws;       // 32768 bf16 = 64 KiB
  float* Cf = (float*)(Bpack + 32768);                 // 256 f32   = 1 KiB
  const bool fits = ws_size >= (size_t)(32768 * 2 + 256 * 4);

  if (fits)
    hipLaunchKernelGGL(prep2_kernel, dim3(128), dim3(TPB), 0, stream,
                       W2, b2, Wd, bd, Bpack, Cf);
  hipLaunchKernelGGL(knn2_kernel, dim3(Bb * 64), dim3(TPB), 0, stream,
                     partial, predicted, outp);
  if (fits)
    hipLaunchKernelGGL(mlp_mfma, dim3((Bb * Nn) / TPB), dim3(TPB), 65536, stream,
                       W1, b1, Bpack, Cf, Wc, bc, outp);
  else
    hipLaunchKernelGGL(mlp_fallback, dim3((Bb * Nn) / TPB), dim3(TPB), 0, stream,
                       W1, b1, W2, b2, Wd, bd, Wc, bc, outp);
}

// Round 4
// 185.082 us; speedup vs baseline: 6.1366x; 1.8078x over previous
//
#include <hip/hip_runtime.h>
#include <hip/hip_bf16.h>
#include <math.h>

#define TPB 256
constexpr int Bb = 8, Mm = 2048, Nn = 8192, HID = 128;

typedef __attribute__((ext_vector_type(8))) short short8;
typedef __attribute__((ext_vector_type(4))) float f32x4;

__device__ __forceinline__ int vzero() { int v; asm("v_mov_b32 %0, 0" : "=v"(v)); return v; }
__device__ __forceinline__ float4 ldg4(const float* __restrict__ p, int idx4, int vz) {
  return ((const float4*)p)[idx4 + vz];
}
__device__ __forceinline__ unsigned short f2b(float x) {
  __hip_bfloat16 h = __float2bfloat16(x);
  return *reinterpret_cast<unsigned short*>(&h);
}

// --- K0: pack fused weights Wf = W2^T·Wd into MFMA-B fragment order (bf16) ---
__global__ __launch_bounds__(TPB) void prep2_kernel(const float* __restrict__ W2,
    const float* __restrict__ b2, const float* __restrict__ Wd,
    const float* __restrict__ bd, unsigned short* __restrict__ Bpack,
    float* __restrict__ Cf) {
  int idx = blockIdx.x * TPB + threadIdx.x;   // 0..32767
  int f = idx >> 9, r = idx & 511, lane = r >> 3, j = r & 7;
  int chunk = f >> 4, ks = (f >> 2) & 3, n = f & 3;
  int k   = ks * 32 + (lane >> 4) * 8 + j;
  int col = chunk * 64 + n * 16 + (lane & 15);
  float acc = 0.f;
  for (int i = 0; i < HID; ++i)
    acc = fmaf(W2[i * HID + k], Wd[i * 256 + col], acc);
  Bpack[idx] = f2b(acc);
  if (idx < 256) {
    float c = bd[idx >> 1];
    for (int i = 0; i < HID; ++i) c = fmaf(b2[i], Wd[i * 256 + idx], c);
    Cf[idx] = c;
  }
}

// bitonic full merge of two sorted-asc 8-lists across lane-xor d (top-8 of union)
#define MERGE_FULL(d)                                                          \
  {                                                                            \
    float p0 = __shfl_xor(u0, d), p1 = __shfl_xor(u1, d),                      \
          p2 = __shfl_xor(u2, d), p3 = __shfl_xor(u3, d),                      \
          p4 = __shfl_xor(u4, d), p5 = __shfl_xor(u5, d),                      \
          p6 = __shfl_xor(u6, d), p7 = __shfl_xor(u7, d);                      \
    float w0 = fmaxf(u0, p7), w1 = fmaxf(u1, p6), w2 = fmaxf(u2, p5),          \
          w3 = fmaxf(u3, p4), w4 = fmaxf(u4, p3), w5 = fmaxf(u5, p2),          \
          w6 = fmaxf(u6, p1), w7 = fmaxf(u7, p0);                              \
    float lo;                                                                  \
    lo = fminf(w0, w4); w4 = fmaxf(w0, w4); w0 = lo;                           \
    lo = fminf(w1, w5); w5 = fmaxf(w1, w5); w1 = lo;                           \
    lo = fminf(w2, w6); w6 = fmaxf(w2, w6); w2 = lo;                           \
    lo = fminf(w3, w7); w7 = fmaxf(w3, w7); w3 = lo;                           \
    lo = fminf(w0, w2); w2 = fmaxf(w0, w2); w0 = lo;                           \
    lo = fminf(w1, w3); w3 = fmaxf(w1, w3); w1 = lo;                           \
    lo = fminf(w4, w6); w6 = fmaxf(w4, w6); w4 = lo;                           \
    lo = fminf(w5, w7); w7 = fmaxf(w5, w7); w5 = lo;                           \
    lo = fminf(w0, w1); w1 = fmaxf(w0, w1); w0 = lo;                           \
    lo = fminf(w2, w3); w3 = fmaxf(w2, w3); w2 = lo;                           \
    lo = fminf(w4, w5); w5 = fmaxf(w4, w5); w4 = lo;                           \
    lo = fminf(w6, w7); w7 = fmaxf(w6, w7); w6 = lo;                           \
    u0 = w0; u1 = w1; u2 = w2; u3 = w3; u4 = w4; u5 = w5; u6 = w6; u7 = w7;    \
  }

// --- K1: exact 8-NN, 4 threads/query, rank by u = dot - 0.5|p|^2 (monotone in -d2)
__global__ __launch_bounds__(TPB) void knn3_kernel(const float* __restrict__ partial,
                                                   const float* __restrict__ predicted,
                                                   float* __restrict__ outp) {
  __shared__ float4 pts[Mm];                  // 32 KiB {x,y,z,-0.5|p|^2}
  const int b  = blockIdx.x >> 7;             // 1024 blocks: 8 b x 128 qt
  const int qt = blockIdx.x & 127;
  const float* pb = partial + (size_t)b * Mm * 3;
  for (int i = threadIdx.x; i < Mm; i += TPB) {
    float x = pb[3 * i], y = pb[3 * i + 1], z = pb[3 * i + 2];
    pts[i] = make_float4(x, y, z, -0.5f * fmaf(x, x, fmaf(y, y, z * z)));
  }
  __syncthreads();

  const int s = threadIdx.x & 3, qi = threadIdx.x >> 2;   // 64 queries/block
  const int q = qt * 64 + qi;
  const float* pq = predicted + ((size_t)b * Nn + q) * 3;
  const float qx = pq[0], qy = pq[1], qz = pq[2];

  // pass A: top-8 LARGEST u, sorted ascending (u0 = 8th largest = threshold)
  float u0 = -INFINITY, u1 = -INFINITY, u2 = -INFINITY, u3 = -INFINITY,
        u4 = -INFINITY, u5 = -INFINITY, u6 = -INFINITY, u7 = -INFINITY;
  #pragma unroll 4
  for (int mm = 0; mm < 512; ++mm) {
    float4 p = pts[s + 4 * mm];               // 4 addrs/wave, disjoint banks
    float u = fmaf(qx, p.x, fmaf(qy, p.y, fmaf(qz, p.z, p.w)));
    if (u > u0) {                             // ascending insert network
      u0 = fminf(u1, fmaxf(u0, u));
      u1 = fminf(u2, fmaxf(u1, u));
      u2 = fminf(u3, fmaxf(u2, u));
      u3 = fminf(u4, fmaxf(u3, u));
      u4 = fminf(u5, fmaxf(u4, u));
      u5 = fminf(u6, fmaxf(u5, u));
      u6 = fminf(u7, fmaxf(u6, u));
      u7 = fmaxf(u7, u);
    }
  }

  // merge the 4 subset lists: full bitonic merge at xor1, min-of-max at xor2
  MERGE_FULL(1);
  float t8u;
  {
    float p0 = __shfl_xor(u0, 2), p1 = __shfl_xor(u1, 2),
          p2 = __shfl_xor(u2, 2), p3 = __shfl_xor(u3, 2),
          p4 = __shfl_xor(u4, 2), p5 = __shfl_xor(u5, 2),
          p6 = __shfl_xor(u6, 2), p7 = __shfl_xor(u7, 2);
    float h0 = fmaxf(u0, p7), h1 = fmaxf(u1, p6), h2 = fmaxf(u2, p5),
          h3 = fmaxf(u3, p4), h4 = fmaxf(u4, p3), h5 = fmaxf(u5, p2),
          h6 = fmaxf(u6, p1), h7 = fmaxf(u7, p0);
    t8u = fminf(fminf(fminf(h0, h1), fminf(h2, h3)),
                fminf(fminf(h4, h5), fminf(h6, h7)));   // 8th largest of union
  }

  // pass B: accumulate winners (u > t8u) and boundary ties (u == t8u)
  float sx = 0.f, sy = 0.f, sz = 0.f, ex = 0.f, ey = 0.f, ez = 0.f;
  int cl = 0, ce = 0;
  #pragma unroll 4
  for (int mm = 0; mm < 512; ++mm) {
    float4 p = pts[s + 4 * mm];
    float u = fmaf(qx, p.x, fmaf(qy, p.y, fmaf(qz, p.z, p.w)));  // bitwise same
    if (u > t8u)       { sx += p.x; sy += p.y; sz += p.z; ++cl; }
    else if (u == t8u) { ex += p.x; ey += p.y; ez += p.z; ++ce; }
  }
  // reduce across the 4 subset lanes
  sx += __shfl_xor(sx, 1); sy += __shfl_xor(sy, 1); sz += __shfl_xor(sz, 1);
  ex += __shfl_xor(ex, 1); ey += __shfl_xor(ey, 1); ez += __shfl_xor(ez, 1);
  cl += __shfl_xor(cl, 1); ce += __shfl_xor(ce, 1);
  sx += __shfl_xor(sx, 2); sy += __shfl_xor(sy, 2); sz += __shfl_xor(sz, 2);
  ex += __shfl_xor(ex, 2); ey += __shfl_xor(ey, 2); ez += __shfl_xor(ez, 2);
  cl += __shfl_xor(cl, 2); ce += __shfl_xor(ce, 2);

  if (s == 0) {
    if (cl + ce != 8) {                       // rare tie overflow: earliest wins
      ex = ey = ez = 0.f; int need = 8 - cl, got = 0;
      for (int m = 0; m < Mm && got < need; ++m) {
        float4 p = pts[m];
        float u = fmaf(qx, p.x, fmaf(qy, p.y, fmaf(qz, p.z, p.w)));
        if (u == t8u) { ex += p.x; ey += p.y; ez += p.z; ++got; }
      }
    }
    float2* co = (float2*)(outp + ((size_t)b * Nn + q) * 6);
    co[0] = make_float2(qx, qy);
    co[1] = make_float2(qz, (sx + ex) * 0.125f);
    co[2] = make_float2((sy + ey) * 0.125f, (sz + ez) * 0.125f);
  }
}

// --- K2: fc1(regs) -> A to LDS(bf16,swizzled) -> MFMA GEMM vs Bpack -> epilogue
__global__ __launch_bounds__(TPB) void mlp_mfma(const float* __restrict__ W1,
    const float* __restrict__ b1, const unsigned short* __restrict__ Bpack,
    const float* __restrict__ Cf, const float* __restrict__ Wc,
    const float* __restrict__ bc, float* __restrict__ outp) {
  extern __shared__ char Alds[];              // 65536 B: A[256 rows][128 k] bf16
  const int tid = threadIdx.x;
  const int row0 = blockIdx.x * TPB;
  const int vz = vzero();

  { // phase 1: fc1 + relu for row = row0 + tid; stage bf16 row to LDS
    const float* rp = outp + (size_t)(row0 + tid) * 6;
    float2 r0 = *(const float2*)rp, r1 = *(const float2*)(rp + 2),
           r2 = *(const float2*)(rp + 4);
    const float c0 = r0.x, c1 = r0.y, c2 = r1.x, c3 = r1.y, c4 = r2.x, c5 = r2.y;
    float4 h4[32];
    #pragma unroll
    for (int j4 = 0; j4 < 32; ++j4) {
      float4 bb = ((const float4*)b1)[j4];
      float4 w0 = ldg4(W1, j4 * 6 + 0, vz), w1 = ldg4(W1, j4 * 6 + 1, vz),
             w2 = ldg4(W1, j4 * 6 + 2, vz), w3 = ldg4(W1, j4 * 6 + 3, vz),
             w4 = ldg4(W1, j4 * 6 + 4, vz), w5 = ldg4(W1, j4 * 6 + 5, vz);
      float a0 = bb.x, a1 = bb.y, a2 = bb.z, a3 = bb.w;
      a0 = fmaf(c0, w0.x, a0); a0 = fmaf(c1, w0.y, a0); a0 = fmaf(c2, w0.z, a0);
      a0 = fmaf(c3, w0.w, a0); a0 = fmaf(c4, w1.x, a0); a0 = fmaf(c5, w1.y, a0);
      a1 = fmaf(c0, w1.z, a1); a1 = fmaf(c1, w1.w, a1); a1 = fmaf(c2, w2.x, a1);
      a1 = fmaf(c3, w2.y, a1); a1 = fmaf(c4, w2.z, a1); a1 = fmaf(c5, w2.w, a1);
      a2 = fmaf(c0, w3.x, a2); a2 = fmaf(c1, w3.y, a2); a2 = fmaf(c2, w3.z, a2);
      a2 = fmaf(c3, w3.w, a2); a2 = fmaf(c4, w4.x, a2); a2 = fmaf(c5, w4.y, a2);
      a3 = fmaf(c0, w4.z, a3); a3 = fmaf(c1, w4.w, a3); a3 = fmaf(c2, w5.x, a3);
      a3 = fmaf(c3, w5.y, a3); a3 = fmaf(c4, w5.z, a3); a3 = fmaf(c5, w5.w, a3);
      h4[j4] = make_float4(fmaxf(a0, 0.f), fmaxf(a1, 0.f), fmaxf(a2, 0.f), fmaxf(a3, 0.f));
    }
    #pragma unroll
    for (int c = 0; c < 16; ++c) {            // 16 B chunks, XOR-swizzled
      float4 lo = h4[c * 2], hi = h4[c * 2 + 1];
      union { unsigned short us[8]; uint4 v; } pk;
      pk.us[0] = f2b(lo.x); pk.us[1] = f2b(lo.y); pk.us[2] = f2b(lo.z); pk.us[3] = f2b(lo.w);
      pk.us[4] = f2b(hi.x); pk.us[5] = f2b(hi.y); pk.us[6] = f2b(hi.z); pk.us[7] = f2b(hi.w);
      int byte = tid * 256 + ((c * 16) ^ ((tid & 7) << 4));
      *(uint4*)(Alds + byte) = pk.v;
    }
  }
  __syncthreads();

  // phase 2: wave computes rows [row0+wid*64, +64) x 256 cols via MFMA
  const int lane = tid & 63, wid = tid >> 6;
  const int g = lane >> 4, cidx = lane & 15;
  float ac[4][4][3] = {};

  for (int chunk = 0; chunk < 4; ++chunk) {
    f32x4 acc[4][4];
    #pragma unroll
    for (int n = 0; n < 4; ++n) {
      float cfv = Cf[chunk * 64 + n * 16 + cidx];
      #pragma unroll
      for (int m = 0; m < 4; ++m) acc[m][n] = (f32x4){cfv, cfv, cfv, cfv};
    }
    #pragma unroll
    for (int ks = 0; ks < 4; ++ks) {
      short8 af[4];
      #pragma unroll
      for (int m = 0; m < 4; ++m) {
        int r = wid * 64 + m * 16 + cidx;
        int byte = r * 256 + ((ks * 64 + g * 16) ^ ((r & 7) << 4));
        af[m] = *(const short8*)(Alds + byte);
      }
      short8 bf[4];
      #pragma unroll
      for (int n = 0; n < 4; ++n)
        bf[n] = *(const short8*)((const char*)Bpack +
                 (((chunk * 4 + ks) * 4 + n) * 1024) + lane * 16);
      #pragma unroll
      for (int m = 0; m < 4; ++m)
        #pragma unroll
        for (int n = 0; n < 4; ++n)
          acc[m][n] = __builtin_amdgcn_mfma_f32_16x16x32_bf16(af[m], bf[n], acc[m][n], 0, 0, 0);
    }
    #pragma unroll
    for (int n = 0; n < 4; ++n) {
      int ot = chunk * 64 + n * 16 + cidx;
      int o = ot >> 1;
      float wc0 = Wc[o], wc1 = Wc[HID + o], wc2 = Wc[2 * HID + o];
      #pragma unroll
      for (int m = 0; m < 4; ++m) {
        #pragma unroll
        for (int i = 0; i < 4; ++i) {
          float v = fmaxf(acc[m][n][i], 0.f);
          ac[m][i][0] = fmaf(v, wc0, ac[m][i][0]);
          ac[m][i][1] = fmaf(v, wc1, ac[m][i][1]);
          ac[m][i][2] = fmaf(v, wc2, ac[m][i][2]);
        }
      }
    }
  }

  const float bc0 = bc[0], bc1 = bc[1], bc2 = bc[2];
  #pragma unroll
  for (int m = 0; m < 4; ++m) {
    #pragma unroll
    for (int i = 0; i < 4; ++i) {
      float s0 = ac[m][i][0], s1 = ac[m][i][1], s2 = ac[m][i][2];
      s0 += __shfl_xor(s0, 2); s0 += __shfl_xor(s0, 4); s0 += __shfl_xor(s0, 8);
      s1 += __shfl_xor(s1, 2); s1 += __shfl_xor(s1, 4); s1 += __shfl_xor(s1, 8);
      s2 += __shfl_xor(s2, 2); s2 += __shfl_xor(s2, 4); s2 += __shfl_xor(s2, 8);
      float o0 = __shfl_xor(s0, 1), o1 = __shfl_xor(s1, 1), o2 = __shfl_xor(s2, 1);
      const bool odd = lane & 1;
      float t00 = odd ? o0 : s0, t01 = odd ? o1 : s1, t02 = odd ? o2 : s2;
      float t10 = odd ? s0 : o0, t11 = odd ? s1 : o1, t12 = odd ? s2 : o2;
      if (cidx == m * 4 + i) {
        int row = row0 + wid * 64 + m * 16 + g * 4 + i;
        float* rp = outp + (size_t)row * 6;
        float px = rp[0], py = rp[1], pz = rp[2];
        rp[0] = px + t00 + bc0; rp[1] = py + t01 + bc1; rp[2] = pz + t02 + bc2;
        rp[3] = px + t10 + bc0; rp[4] = py + t11 + bc1; rp[5] = pz + t12 + bc2;
      }
    }
  }
}

// --- correctness-only fallback if ws too small (no ws use) ------------------
__global__ __launch_bounds__(TPB) void mlp_fallback(
    const float* __restrict__ W1, const float* __restrict__ b1,
    const float* __restrict__ W2, const float* __restrict__ b2,
    const float* __restrict__ Wd, const float* __restrict__ bd,
    const float* __restrict__ Wc, const float* __restrict__ bc,
    float* __restrict__ outp) {
  const int row = blockIdx.x * TPB + threadIdx.x;
  float2* rp = (float2*)(outp + (size_t)row * 6);
  float2 r0 = rp[0], r1 = rp[1], r2 = rp[2];
  float cc[6] = {r0.x, r0.y, r1.x, r1.y, r2.x, r2.y};
  float h[HID];
  for (int j = 0; j < HID; ++j) {
    float a = b1[j];
    for (int c = 0; c < 6; ++c) a = fmaf(cc[c], W1[j * 6 + c], a);
    h[j] = fmaxf(a, 0.f);
  }
  float sd[HID];
  for (int i = 0; i < HID; ++i) {
    float a = b2[i];
    for (int j = 0; j < HID; ++j) a = fmaf(h[j], W2[i * HID + j], a);
    sd[i] = a;
  }
  float ov[3][2] = {};
  for (int oc = 0; oc < HID; ++oc)
    for (int t = 0; t < 2; ++t) {
      float a = bd[oc];
      for (int i = 0; i < HID; ++i) a = fmaf(sd[i], Wd[i * 256 + oc * 2 + t], a);
      a = fmaxf(a, 0.f);
      for (int c = 0; c < 3; ++c) ov[c][t] = fmaf(a, Wc[c * HID + oc], ov[c][t]);
    }
  rp[0] = make_float2(cc[0] + ov[0][0] + bc[0], cc[1] + ov[1][0] + bc[1]);
  rp[1] = make_float2(cc[2] + ov[2][0] + bc[2], cc[0] + ov[0][1] + bc[0]);
  rp[2] = make_float2(cc[1] + ov[1][1] + bc[1], cc[2] + ov[2][1] + bc[2]);
}

extern "C" void kernel_launch(void* const* d_in, const int* in_sizes, int n_in,
                              void* d_out, int out_size, void* d_ws, size_t ws_size,
                              hipStream_t stream) {
  const float* partial   = (const float*)d_in[0];
  const float* predicted = (const float*)d_in[1];
  const float* W1 = (const float*)d_in[2];
  const float* b1 = (const float*)d_in[3];
  const float* W2 = (const float*)d_in[4];
  const float* b2 = (const float*)d_in[5];
  const float* Wd = (const float*)d_in[6];
  const float* bd = (const float*)d_in[7];
  const float* Wc = (const float*)d_in[8];
  const float* bc = (const float*)d_in[9];
  float* outp = (float*)d_out;

  unsigned short* Bpack = (unsigned short*)d_ws;       // 32768 bf16 = 64 KiB
  float* Cf = (float*)(Bpack + 32768);                 // 256 f32   = 1 KiB
  const bool fits = ws_size >= (size_t)(32768 * 2 + 256 * 4);

  if (fits)
    hipLaunchKernelGGL(prep2_kernel, dim3(128), dim3(TPB), 0, stream,
                       W2, b2, Wd, bd, Bpack, Cf);
  hipLaunchKernelGGL(knn3_kernel, dim3(Bb * 128), dim3(TPB), 0, stream,
                     partial, predicted, outp);
  if (fits)
    hipLaunchKernelGGL(mlp_mfma, dim3((Bb * Nn) / TPB), dim3(TPB), 65536, stream,
                       W1, b1, Bpack, Cf, Wc, bc, outp);
  else
    hipLaunchKernelGGL(mlp_fallback, dim3((Bb * Nn) / TPB), dim3(TPB), 0, stream,
                       W1, b1, W2, b2, Wd, bd, Wc, bc, outp);
}

// Round 5
// 123.966 us; speedup vs baseline: 9.1619x; 1.4930x over previous
//
#include <hip/hip_runtime.h>
#include <hip/hip_bf16.h>
#include <math.h>

#define TPB 256
constexpr int Bb = 8, Mm = 2048, Nn = 8192, HID = 128;

typedef __attribute__((ext_vector_type(8))) short short8;
typedef __attribute__((ext_vector_type(4))) float f32x4;

__device__ __forceinline__ int vzero() { int v; asm("v_mov_b32 %0, 0" : "=v"(v)); return v; }
__device__ __forceinline__ float4 ldg4(const float* __restrict__ p, int idx4, int vz) {
  return ((const float4*)p)[idx4 + vz];
}
__device__ __forceinline__ unsigned short f2b(float x) {
  __hip_bfloat16 h = __float2bfloat16(x);
  return *reinterpret_cast<unsigned short*>(&h);
}

// --- K0: pack fused weights Wf = W2^T·Wd into MFMA-B fragment order (bf16) ---
__global__ __launch_bounds__(TPB) void prep2_kernel(const float* __restrict__ W2,
    const float* __restrict__ b2, const float* __restrict__ Wd,
    const float* __restrict__ bd, unsigned short* __restrict__ Bpack,
    float* __restrict__ Cf) {
  int idx = blockIdx.x * TPB + threadIdx.x;   // 0..32767
  int f = idx >> 9, r = idx & 511, lane = r >> 3, j = r & 7;
  int chunk = f >> 4, ks = (f >> 2) & 3, n = f & 3;
  int k   = ks * 32 + (lane >> 4) * 8 + j;
  int col = chunk * 64 + n * 16 + (lane & 15);
  float acc = 0.f;
  for (int i = 0; i < HID; ++i)
    acc = fmaf(W2[i * HID + k], Wd[i * 256 + col], acc);
  Bpack[idx] = f2b(acc);
  if (idx < 256) {
    float c = bd[idx >> 1];
    for (int i = 0; i < HID; ++i) c = fmaf(b2[i], Wd[i * 256 + idx], c);
    Cf[idx] = c;
  }
}

// bitonic full merge of two sorted-asc 8-lists across lane-xor d (top-8 of union)
#define MERGE_FULL(d)                                                          \
  {                                                                            \
    float p0 = __shfl_xor(u0, d), p1 = __shfl_xor(u1, d),                      \
          p2 = __shfl_xor(u2, d), p3 = __shfl_xor(u3, d),                      \
          p4 = __shfl_xor(u4, d), p5 = __shfl_xor(u5, d),                      \
          p6 = __shfl_xor(u6, d), p7 = __shfl_xor(u7, d);                      \
    float w0 = fmaxf(u0, p7), w1 = fmaxf(u1, p6), w2 = fmaxf(u2, p5),          \
          w3 = fmaxf(u3, p4), w4 = fmaxf(u4, p3), w5 = fmaxf(u5, p2),          \
          w6 = fmaxf(u6, p1), w7 = fmaxf(u7, p0);                              \
    float lo;                                                                  \
    lo = fminf(w0, w4); w4 = fmaxf(w0, w4); w0 = lo;                           \
    lo = fminf(w1, w5); w5 = fmaxf(w1, w5); w1 = lo;                           \
    lo = fminf(w2, w6); w6 = fmaxf(w2, w6); w2 = lo;                           \
    lo = fminf(w3, w7); w7 = fmaxf(w3, w7); w3 = lo;                           \
    lo = fminf(w0, w2); w2 = fmaxf(w0, w2); w0 = lo;                           \
    lo = fminf(w1, w3); w3 = fmaxf(w1, w3); w1 = lo;                           \
    lo = fminf(w4, w6); w6 = fmaxf(w4, w6); w4 = lo;                           \
    lo = fminf(w5, w7); w7 = fmaxf(w5, w7); w5 = lo;                           \
    lo = fminf(w0, w1); w1 = fmaxf(w0, w1); w0 = lo;                           \
    lo = fminf(w2, w3); w3 = fmaxf(w2, w3); w2 = lo;                           \
    lo = fminf(w4, w5); w5 = fmaxf(w4, w5); w4 = lo;                           \
    lo = fminf(w6, w7); w7 = fmaxf(w6, w7); w6 = lo;                           \
    u0 = w0; u1 = w1; u2 = w2; u3 = w3; u4 = w4; u5 = w5; u6 = w6; u7 = w7;    \
  }

// --- K1: exact 8-NN, 4 threads/query, rank by u = dot - 0.5|p|^2 ------------
// Insert via 8 independent v_med3_f32 (branchless; identity when u <= u0).
__global__ __launch_bounds__(TPB) void knn4_kernel(const float* __restrict__ partial,
                                                   const float* __restrict__ predicted,
                                                   float* __restrict__ outp) {
  __shared__ float4 pts[Mm];                  // 32 KiB {x,y,z,-0.5|p|^2}
  const int b  = blockIdx.x >> 7;             // 1024 blocks: 8 b x 128 qt
  const int qt = blockIdx.x & 127;
  const float* pb = partial + (size_t)b * Mm * 3;
  for (int i = threadIdx.x; i < Mm; i += TPB) {
    float x = pb[3 * i], y = pb[3 * i + 1], z = pb[3 * i + 2];
    pts[i] = make_float4(x, y, z, -0.5f * fmaf(x, x, fmaf(y, y, z * z)));
  }
  __syncthreads();

  const int s = threadIdx.x & 3, qi = threadIdx.x >> 2;   // 64 queries/block
  const int q = qt * 64 + qi;
  const float* pq = predicted + ((size_t)b * Nn + q) * 3;
  const float qx = pq[0], qy = pq[1], qz = pq[2];
  const float4* ps = pts + s;                 // subset base (stride 4)

  // pass A: top-8 LARGEST u, ascending regs (u0 = running 8th largest)
  float u0 = -INFINITY, u1 = -INFINITY, u2 = -INFINITY, u3 = -INFINITY,
        u4 = -INFINITY, u5 = -INFINITY, u6 = -INFINITY, u7 = -INFINITY;
  #pragma unroll 8
  for (int mm = 0; mm < 512; ++mm) {
    float4 p = ps[4 * mm];                    // 4 addrs/wave, disjoint banks
    float u = fmaf(qx, p.x, fmaf(qy, p.y, fmaf(qz, p.z, p.w)));
    float n0 = __builtin_amdgcn_fmed3f(u, u0, u1);
    float n1 = __builtin_amdgcn_fmed3f(u, u1, u2);
    float n2 = __builtin_amdgcn_fmed3f(u, u2, u3);
    float n3 = __builtin_amdgcn_fmed3f(u, u3, u4);
    float n4 = __builtin_amdgcn_fmed3f(u, u4, u5);
    float n5 = __builtin_amdgcn_fmed3f(u, u5, u6);
    float n6 = __builtin_amdgcn_fmed3f(u, u6, u7);
    float n7 = fmaxf(u7, u);
    u0 = n0; u1 = n1; u2 = n2; u3 = n3; u4 = n4; u5 = n5; u6 = n6; u7 = n7;
  }

  // merge the 4 subset lists: full bitonic merge at xor1, min-of-max at xor2
  MERGE_FULL(1);
  float t8u;
  {
    float p0 = __shfl_xor(u0, 2), p1 = __shfl_xor(u1, 2),
          p2 = __shfl_xor(u2, 2), p3 = __shfl_xor(u3, 2),
          p4 = __shfl_xor(u4, 2), p5 = __shfl_xor(u5, 2),
          p6 = __shfl_xor(u6, 2), p7 = __shfl_xor(u7, 2);
    float h0 = fmaxf(u0, p7), h1 = fmaxf(u1, p6), h2 = fmaxf(u2, p5),
          h3 = fmaxf(u3, p4), h4 = fmaxf(u4, p3), h5 = fmaxf(u5, p2),
          h6 = fmaxf(u6, p1), h7 = fmaxf(u7, p0);
    t8u = fminf(fminf(fminf(h0, h1), fminf(h2, h3)),
                fminf(fminf(h4, h5), fminf(h6, h7)));   // 8th largest of union
  }

  // pass B: accumulate winners (u > t8u) and boundary ties (u == t8u)
  float sx = 0.f, sy = 0.f, sz = 0.f, ex = 0.f, ey = 0.f, ez = 0.f;
  int cl = 0, ce = 0;
  #pragma unroll 4
  for (int mm = 0; mm < 512; ++mm) {
    float4 p = ps[4 * mm];
    float u = fmaf(qx, p.x, fmaf(qy, p.y, fmaf(qz, p.z, p.w)));  // bitwise same
    if (u > t8u)       { sx += p.x; sy += p.y; sz += p.z; ++cl; }
    else if (u == t8u) { ex += p.x; ey += p.y; ez += p.z; ++ce; }
  }
  // reduce across the 4 subset lanes
  sx += __shfl_xor(sx, 1); sy += __shfl_xor(sy, 1); sz += __shfl_xor(sz, 1);
  ex += __shfl_xor(ex, 1); ey += __shfl_xor(ey, 1); ez += __shfl_xor(ez, 1);
  cl += __shfl_xor(cl, 1); ce += __shfl_xor(ce, 1);
  sx += __shfl_xor(sx, 2); sy += __shfl_xor(sy, 2); sz += __shfl_xor(sz, 2);
  ex += __shfl_xor(ex, 2); ey += __shfl_xor(ey, 2); ez += __shfl_xor(ez, 2);
  cl += __shfl_xor(cl, 2); ce += __shfl_xor(ce, 2);

  if (s == 0) {
    if (cl + ce != 8) {                       // rare tie overflow: earliest wins
      ex = ey = ez = 0.f; int need = 8 - cl, got = 0;
      for (int m = 0; m < Mm && got < need; ++m) {
        float4 p = pts[m];
        float u = fmaf(qx, p.x, fmaf(qy, p.y, fmaf(qz, p.z, p.w)));
        if (u == t8u) { ex += p.x; ey += p.y; ez += p.z; ++got; }
      }
    }
    float2* co = (float2*)(outp + ((size_t)b * Nn + q) * 6);
    co[0] = make_float2(qx, qy);
    co[1] = make_float2(qz, (sx + ex) * 0.125f);
    co[2] = make_float2((sy + ey) * 0.125f, (sz + ez) * 0.125f);
  }
}

// --- K2: fc1(regs) -> A to LDS(bf16,swizzled) -> MFMA GEMM vs Bpack -> epilogue
__global__ __launch_bounds__(TPB) void mlp_mfma(const float* __restrict__ W1,
    const float* __restrict__ b1, const unsigned short* __restrict__ Bpack,
    const float* __restrict__ Cf, const float* __restrict__ Wc,
    const float* __restrict__ bc, float* __restrict__ outp) {
  extern __shared__ char Alds[];              // 65536 B: A[256 rows][128 k] bf16
  const int tid = threadIdx.x;
  const int row0 = blockIdx.x * TPB;
  const int vz = vzero();

  { // phase 1: fc1 + relu for row = row0 + tid; stage bf16 row to LDS
    const float* rp = outp + (size_t)(row0 + tid) * 6;
    float2 r0 = *(const float2*)rp, r1 = *(const float2*)(rp + 2),
           r2 = *(const float2*)(rp + 4);
    const float c0 = r0.x, c1 = r0.y, c2 = r1.x, c3 = r1.y, c4 = r2.x, c5 = r2.y;
    float4 h4[32];
    #pragma unroll
    for (int j4 = 0; j4 < 32; ++j4) {
      float4 bb = ((const float4*)b1)[j4];
      float4 w0 = ldg4(W1, j4 * 6 + 0, vz), w1 = ldg4(W1, j4 * 6 + 1, vz),
             w2 = ldg4(W1, j4 * 6 + 2, vz), w3 = ldg4(W1, j4 * 6 + 3, vz),
             w4 = ldg4(W1, j4 * 6 + 4, vz), w5 = ldg4(W1, j4 * 6 + 5, vz);
      float a0 = bb.x, a1 = bb.y, a2 = bb.z, a3 = bb.w;
      a0 = fmaf(c0, w0.x, a0); a0 = fmaf(c1, w0.y, a0); a0 = fmaf(c2, w0.z, a0);
      a0 = fmaf(c3, w0.w, a0); a0 = fmaf(c4, w1.x, a0); a0 = fmaf(c5, w1.y, a0);
      a1 = fmaf(c0, w1.z, a1); a1 = fmaf(c1, w1.w, a1); a1 = fmaf(c2, w2.x, a1);
      a1 = fmaf(c3, w2.y, a1); a1 = fmaf(c4, w2.z, a1); a1 = fmaf(c5, w2.w, a1);
      a2 = fmaf(c0, w3.x, a2); a2 = fmaf(c1, w3.y, a2); a2 = fmaf(c2, w3.z, a2);
      a2 = fmaf(c3, w3.w, a2); a2 = fmaf(c4, w4.x, a2); a2 = fmaf(c5, w4.y, a2);
      a3 = fmaf(c0, w4.z, a3); a3 = fmaf(c1, w4.w, a3); a3 = fmaf(c2, w5.x, a3);
      a3 = fmaf(c3, w5.y, a3); a3 = fmaf(c4, w5.z, a3); a3 = fmaf(c5, w5.w, a3);
      h4[j4] = make_float4(fmaxf(a0, 0.f), fmaxf(a1, 0.f), fmaxf(a2, 0.f), fmaxf(a3, 0.f));
    }
    #pragma unroll
    for (int c = 0; c < 16; ++c) {            // 16 B chunks, XOR-swizzled
      float4 lo = h4[c * 2], hi = h4[c * 2 + 1];
      union { unsigned short us[8]; uint4 v; } pk;
      pk.us[0] = f2b(lo.x); pk.us[1] = f2b(lo.y); pk.us[2] = f2b(lo.z); pk.us[3] = f2b(lo.w);
      pk.us[4] = f2b(hi.x); pk.us[5] = f2b(hi.y); pk.us[6] = f2b(hi.z); pk.us[7] = f2b(hi.w);
      int byte = tid * 256 + ((c * 16) ^ ((tid & 7) << 4));
      *(uint4*)(Alds + byte) = pk.v;
    }
  }
  __syncthreads();

  // phase 2: wave computes rows [row0+wid*64, +64) x 256 cols via MFMA
  const int lane = tid & 63, wid = tid >> 6;
  const int g = lane >> 4, cidx = lane & 15;
  float ac[4][4][3] = {};

  for (int chunk = 0; chunk < 4; ++chunk) {
    f32x4 acc[4][4];
    #pragma unroll
    for (int n = 0; n < 4; ++n) {
      float cfv = Cf[chunk * 64 + n * 16 + cidx];
      #pragma unroll
      for (int m = 0; m < 4; ++m) acc[m][n] = (f32x4){cfv, cfv, cfv, cfv};
    }
    #pragma unroll
    for (int ks = 0; ks < 4; ++ks) {
      short8 af[4];
      #pragma unroll
      for (int m = 0; m < 4; ++m) {
        int r = wid * 64 + m * 16 + cidx;
        int byte = r * 256 + ((ks * 64 + g * 16) ^ ((r & 7) << 4));
        af[m] = *(const short8*)(Alds + byte);
      }
      short8 bf[4];
      #pragma unroll
      for (int n = 0; n < 4; ++n)
        bf[n] = *(const short8*)((const char*)Bpack +
                 (((chunk * 4 + ks) * 4 + n) * 1024) + lane * 16);
      #pragma unroll
      for (int m = 0; m < 4; ++m)
        #pragma unroll
        for (int n = 0; n < 4; ++n)
          acc[m][n] = __builtin_amdgcn_mfma_f32_16x16x32_bf16(af[m], bf[n], acc[m][n], 0, 0, 0);
    }
    #pragma unroll
    for (int n = 0; n < 4; ++n) {
      int ot = chunk * 64 + n * 16 + cidx;
      int o = ot >> 1;
      float wc0 = Wc[o], wc1 = Wc[HID + o], wc2 = Wc[2 * HID + o];
      #pragma unroll
      for (int m = 0; m < 4; ++m) {
        #pragma unroll
        for (int i = 0; i < 4; ++i) {
          float v = fmaxf(acc[m][n][i], 0.f);
          ac[m][i][0] = fmaf(v, wc0, ac[m][i][0]);
          ac[m][i][1] = fmaf(v, wc1, ac[m][i][1]);
          ac[m][i][2] = fmaf(v, wc2, ac[m][i][2]);
        }
      }
    }
  }

  const float bc0 = bc[0], bc1 = bc[1], bc2 = bc[2];
  #pragma unroll
  for (int m = 0; m < 4; ++m) {
    #pragma unroll
    for (int i = 0; i < 4; ++i) {
      float s0 = ac[m][i][0], s1 = ac[m][i][1], s2 = ac[m][i][2];
      s0 += __shfl_xor(s0, 2); s0 += __shfl_xor(s0, 4); s0 += __shfl_xor(s0, 8);
      s1 += __shfl_xor(s1, 2); s1 += __shfl_xor(s1, 4); s1 += __shfl_xor(s1, 8);
      s2 += __shfl_xor(s2, 2); s2 += __shfl_xor(s2, 4); s2 += __shfl_xor(s2, 8);
      float o0 = __shfl_xor(s0, 1), o1 = __shfl_xor(s1, 1), o2 = __shfl_xor(s2, 1);
      const bool odd = lane & 1;
      float t00 = odd ? o0 : s0, t01 = odd ? o1 : s1, t02 = odd ? o2 : s2;
      float t10 = odd ? s0 : o0, t11 = odd ? s1 : o1, t12 = odd ? s2 : o2;
      if (cidx == m * 4 + i) {
        int row = row0 + wid * 64 + m * 16 + g * 4 + i;
        float* rp = outp + (size_t)row * 6;
        float px = rp[0], py = rp[1], pz = rp[2];
        rp[0] = px + t00 + bc0; rp[1] = py + t01 + bc1; rp[2] = pz + t02 + bc2;
        rp[3] = px + t10 + bc0; rp[4] = py + t11 + bc1; rp[5] = pz + t12 + bc2;
      }
    }
  }
}

// --- correctness-only fallback if ws too small (no ws use) ------------------
__global__ __launch_bounds__(TPB) void mlp_fallback(
    const float* __restrict__ W1, const float* __restrict__ b1,
    const float* __restrict__ W2, const float* __restrict__ b2,
    const float* __restrict__ Wd, const float* __restrict__ bd,
    const float* __restrict__ Wc, const float* __restrict__ bc,
    float* __restrict__ outp) {
  const int row = blockIdx.x * TPB + threadIdx.x;
  float2* rp = (float2*)(outp + (size_t)row * 6);
  float2 r0 = rp[0], r1 = rp[1], r2 = rp[2];
  float cc[6] = {r0.x, r0.y, r1.x, r1.y, r2.x, r2.y};
  float h[HID];
  for (int j = 0; j < HID; ++j) {
    float a = b1[j];
    for (int c = 0; c < 6; ++c) a = fmaf(cc[c], W1[j * 6 + c], a);
    h[j] = fmaxf(a, 0.f);
  }
  float sd[HID];
  for (int i = 0; i < HID; ++i) {
    float a = b2[i];
    for (int j = 0; j < HID; ++j) a = fmaf(h[j], W2[i * HID + j], a);
    sd[i] = a;
  }
  float ov[3][2] = {};
  for (int oc = 0; oc < HID; ++oc)
    for (int t = 0; t < 2; ++t) {
      float a = bd[oc];
      for (int i = 0; i < HID; ++i) a = fmaf(sd[i], Wd[i * 256 + oc * 2 + t], a);
      a = fmaxf(a, 0.f);
      for (int c = 0; c < 3; ++c) ov[c][t] = fmaf(a, Wc[c * HID + oc], ov[c][t]);
    }
  rp[0] = make_float2(cc[0] + ov[0][0] + bc[0], cc[1] + ov[1][0] + bc[1]);
  rp[1] = make_float2(cc[2] + ov[2][0] + bc[2], cc[0] + ov[0][1] + bc[0]);
  rp[2] = make_float2(cc[1] + ov[1][1] + bc[1], cc[2] + ov[2][1] + bc[2]);
}

extern "C" void kernel_launch(void* const* d_in, const int* in_sizes, int n_in,
                              void* d_out, int out_size, void* d_ws, size_t ws_size,
                              hipStream_t stream) {
  const float* partial   = (const float*)d_in[0];
  const float* predicted = (const float*)d_in[1];
  const float* W1 = (const float*)d_in[2];
  const float* b1 = (const float*)d_in[3];
  const float* W2 = (const float*)d_in[4];
  const float* b2 = (const float*)d_in[5];
  const float* Wd = (const float*)d_in[6];
  const float* bd = (const float*)d_in[7];
  const float* Wc = (const float*)d_in[8];
  const float* bc = (const float*)d_in[9];
  float* outp = (float*)d_out;

  unsigned short* Bpack = (unsigned short*)d_ws;       // 32768 bf16 = 64 KiB
  float* Cf = (float*)(Bpack + 32768);                 // 256 f32   = 1 KiB
  const bool fits = ws_size >= (size_t)(32768 * 2 + 256 * 4);

  if (fits)
    hipLaunchKernelGGL(prep2_kernel, dim3(128), dim3(TPB), 0, stream,
                       W2, b2, Wd, bd, Bpack, Cf);
  hipLaunchKernelGGL(knn4_kernel, dim3(Bb * 128), dim3(TPB), 0, stream,
                     partial, predicted, outp);
  if (fits)
    hipLaunchKernelGGL(mlp_mfma, dim3((Bb * Nn) / TPB), dim3(TPB), 65536, stream,
                       W1, b1, Bpack, Cf, Wc, bc, outp);
  else
    hipLaunchKernelGGL(mlp_fallback, dim3((Bb * Nn) / TPB), dim3(TPB), 0, stream,
                       W1, b1, W2, b2, Wd, bd, Wc, bc, outp);
}